// Round 1
// baseline (211.769 us; speedup 1.0000x reference)
//
#include <hip/hip_runtime.h>
#include <math.h>

#define N_CLASS 200000
#define DIM     192
#define BATCH   64
#define NSLOT   3
#define M_ROWS  192            // B*N
#define BN      64             // classes per block
#define BK      16             // K tile
#define NBLK    (N_CLASS/BN)   // 3125

#define S_SCALE 30.0f
#define COS_M   0.9800665778412416f
#define SIN_M   0.19866933079506122f
#define TH_C    (-0.9800665778412416f)
#define MM_C    0.039733866159012245f

__device__ __forceinline__ float wave_reduce_sum(float v) {
#pragma unroll
    for (int o = 32; o > 0; o >>= 1) v += __shfl_xor(v, o, 64);
    return v;
}

// ---- normalize pred_embs -> xn [row][k] and xt [k][row] ----
__global__ void k_normalize(const float* __restrict__ pe,
                            float* __restrict__ xn, float* __restrict__ xt) {
    int r = blockIdx.x;      // 0..191
    int l = threadIdx.x;     // 0..63
    float v0 = pe[r * DIM + l];
    float v1 = pe[r * DIM + l + 64];
    float v2 = pe[r * DIM + l + 128];
    float ss = wave_reduce_sum(v0 * v0 + v1 * v1 + v2 * v2);
    float rn = 1.0f / fmaxf(sqrtf(ss), 1e-6f);
    float a0 = v0 * rn, a1 = v1 * rn, a2 = v2 * rn;
    xn[r * DIM + l]        = a0;
    xn[r * DIM + l + 64]   = a1;
    xn[r * DIM + l + 128]  = a2;
    xt[(l) * M_ROWS + r]       = a0;
    xt[(l + 64) * M_ROWS + r]  = a1;
    xt[(l + 128) * M_ROWS + r] = a2;
}

// ---- gt-label cosines: cosl[row][s] = clip(dot(x_row, w_label/||w||)) ----
__global__ void k_gtcos(const float* __restrict__ weight, const int* __restrict__ gt,
                        const float* __restrict__ xn, float* __restrict__ cosl) {
    int i = blockIdx.x;             // b*S + s
    int b = i / NSLOT, s = i - b * NSLOT;
    int l = threadIdx.x;
    int lab = gt[b * NSLOT + s];
    const float* w = weight + (long)lab * DIM;
    float w0 = w[l], w1 = w[l + 64], w2 = w[l + 128];
    float ss = wave_reduce_sum(w0 * w0 + w1 * w1 + w2 * w2);
    float rn = 1.0f / fmaxf(sqrtf(ss), 1e-6f);
    for (int n = 0; n < NSLOT; ++n) {
        const float* x = xn + (b * NSLOT + n) * DIM;
        float d = wave_reduce_sum(w0 * x[l] + w1 * x[l + 64] + w2 * x[l + 128]);
        float c = fminf(fmaxf(d * rn, -1.0f + 1e-7f), 1.0f - 1e-7f);
        if (l == 0) cosl[(b * NSLOT + n) * NSLOT + s] = c;
    }
}

// ---- fused GEMM (M=192 x BN=64 per block, K=192) + exp-sum epilogue ----
__global__ __launch_bounds__(256) void k_main(const float* __restrict__ weight,
                                              const float* __restrict__ xt,
                                              float* __restrict__ partials) {
    __shared__ float xs[BK * M_ROWS];   // 16x192
    __shared__ float wsl[BK * BN];      // 16x64, [k][c]
    __shared__ float ssq[BN * 4];       // per-class sumsq parts
    __shared__ float red[M_ROWS * 16];  // row-sum reduction

    const int tid = threadIdx.x;
    const int tc = tid & 15;            // col group (4 classes)
    const int tr = tid >> 4;            // row group (12 rows)
    const int c0 = blockIdx.x * BN;
    const int cl = tid & 63;            // staging class
    const int k4 = tid >> 6;            // staging k-quad (0..3)

    float acc[12][4];
#pragma unroll
    for (int i = 0; i < 12; ++i)
#pragma unroll
        for (int j = 0; j < 4; ++j) acc[i][j] = 0.0f;
    float sq = 0.0f;

    for (int kk = 0; kk < DIM; kk += BK) {
        __syncthreads();
        // stage x slice [kk..kk+15][0..191] (contiguous, coalesced)
#pragma unroll
        for (int j = 0; j < 3; ++j) {
            int f4 = tid + j * 256;
            float4 v = reinterpret_cast<const float4*>(xt + kk * M_ROWS)[f4];
            reinterpret_cast<float4*>(xs)[f4] = v;
        }
        // stage w tile transposed to [k][c]; accumulate sumsq for norms
        {
            float4 v = *reinterpret_cast<const float4*>(
                weight + (long)(c0 + cl) * DIM + kk + k4 * 4);
            sq += v.x * v.x + v.y * v.y + v.z * v.z + v.w * v.w;
            wsl[(k4 * 4 + 0) * BN + cl] = v.x;
            wsl[(k4 * 4 + 1) * BN + cl] = v.y;
            wsl[(k4 * 4 + 2) * BN + cl] = v.z;
            wsl[(k4 * 4 + 3) * BN + cl] = v.w;
        }
        __syncthreads();
#pragma unroll 4
        for (int k = 0; k < BK; ++k) {
            float4 xa = *reinterpret_cast<const float4*>(&xs[k * M_ROWS + tr * 12]);
            float4 xb = *reinterpret_cast<const float4*>(&xs[k * M_ROWS + tr * 12 + 4]);
            float4 xc = *reinterpret_cast<const float4*>(&xs[k * M_ROWS + tr * 12 + 8]);
            float4 wf = *reinterpret_cast<const float4*>(&wsl[k * BN + tc * 4]);
            float xv[12] = {xa.x, xa.y, xa.z, xa.w, xb.x, xb.y, xb.z, xb.w,
                            xc.x, xc.y, xc.z, xc.w};
            float wv[4] = {wf.x, wf.y, wf.z, wf.w};
#pragma unroll
            for (int i = 0; i < 12; ++i)
#pragma unroll
                for (int j = 0; j < 4; ++j) acc[i][j] += xv[i] * wv[j];
        }
    }

    // class norms
    ssq[cl * 4 + k4] = sq;
    __syncthreads();

    float rowpart[12];
#pragma unroll
    for (int i = 0; i < 12; ++i) rowpart[i] = 0.0f;
#pragma unroll
    for (int j = 0; j < 4; ++j) {
        int c = tc * 4 + j;
        float s = ssq[c * 4 + 0] + ssq[c * 4 + 1] + ssq[c * 4 + 2] + ssq[c * 4 + 3];
        float rn = 1.0f / fmaxf(sqrtf(s), 1e-6f);
#pragma unroll
        for (int i = 0; i < 12; ++i) {
            float cs = fminf(fmaxf(acc[i][j] * rn, -1.0f + 1e-7f), 1.0f - 1e-7f);
            rowpart[i] += __expf(S_SCALE * cs - 30.0f);  // exp(30c-30): no overflow
        }
    }
#pragma unroll
    for (int i = 0; i < 12; ++i) red[(tr * 12 + i) * 16 + tc] = rowpart[i];
    __syncthreads();
    if (tid < M_ROWS) {
        float s = 0.0f;
#pragma unroll
        for (int q = 0; q < 16; ++q) s += red[tid * 16 + q];
        partials[(long)blockIdx.x * M_ROWS + tid] = s;
    }
}

// ---- deterministic reduce over 3125 block partials per row ----
__global__ void k_reduce(const float* __restrict__ partials, float* __restrict__ sum_exp) {
    int r = blockIdx.x;
    float s = 0.0f;
    for (int i = threadIdx.x; i < NBLK; i += 256)
        s += partials[(long)i * M_ROWS + r];
    s = wave_reduce_sum(s);
    __shared__ float wsm[4];
    int wid = threadIdx.x >> 6;
    if ((threadIdx.x & 63) == 0) wsm[wid] = s;
    __syncthreads();
    if (threadIdx.x == 0) sum_exp[r] = wsm[0] + wsm[1] + wsm[2] + wsm[3];
}

// ---- ce matrix, permutation argmin, final losses ----
__global__ void k_final(const float* __restrict__ sum_exp, const float* __restrict__ cosl,
                        const float* __restrict__ pred_ps, float* __restrict__ out) {
    int b = threadIdx.x;  // 0..63, one wave
    const int perms[6][3] = {{0,1,2},{0,2,1},{1,0,2},{1,2,0},{2,0,1},{2,1,0}};
    float ce[3][3];  // [n][s]
#pragma unroll
    for (int n = 0; n < 3; ++n) {
        float lse = 30.0f + logf(sum_exp[b * 3 + n]);
#pragma unroll
        for (int s = 0; s < 3; ++s) {
            float c  = cosl[(b * 3 + n) * 3 + s];
            float sl = sqrtf(fmaxf(1.0f - c * c, 1e-7f));
            float phi = c * COS_M - sl * SIN_M;
            phi = (c > TH_C) ? phi : (c - MM_C);
            float lm = lse + log1pf(expf(S_SCALE * phi - lse) - expf(S_SCALE * c - lse));
            ce[n][s] = lm - S_SCALE * phi;
        }
    }
    float best = 1e30f;
    int bp = 0;
#pragma unroll
    for (int p = 0; p < 6; ++p) {
        float cost = ce[perms[p][0]][0] + ce[perms[p][1]][1] + ce[perms[p][2]][2];
        if (cost < best) { best = cost; bp = p; }  // first-min wins, matches argmin
    }
    float lspk = (ce[perms[bp][0]][0] + ce[perms[bp][1]][1] + ce[perms[bp][2]][2]) / 3.0f;

    float p0 = fminf(fmaxf(pred_ps[b * 4 + 0], 1e-6f), 1.0f - 1e-6f);
    float p1 = fminf(fmaxf(pred_ps[b * 4 + 1], 1e-6f), 1.0f - 1e-6f);
    float p2 = fminf(fmaxf(pred_ps[b * 4 + 2], 1e-6f), 1.0f - 1e-6f);
    float p3 = fminf(fmaxf(pred_ps[b * 4 + 3], 1e-6f), 1.0f - 1e-6f);
    float lcnt = -(log1pf(-p0) + log1pf(-p1) + log1pf(-p2) + logf(p3)) * 0.25f;

    float ts  = wave_reduce_sum(lspk) / 64.0f;
    float tcn = wave_reduce_sum(lcnt) / 64.0f;
    if (b == 0) {
        out[0] = ts + 0.1f * tcn;
        out[1] = ts;
        out[2] = tcn;
    }
}

extern "C" void kernel_launch(void* const* d_in, const int* in_sizes, int n_in,
                              void* d_out, int out_size, void* d_ws, size_t ws_size,
                              hipStream_t stream) {
    const float* pred_embs = (const float*)d_in[0];
    const float* pred_ps   = (const float*)d_in[1];
    const int*   gt_labels = (const int*)d_in[2];
    const float* weight    = (const float*)d_in[3];
    float* out = (float*)d_out;
    float* ws  = (float*)d_ws;

    float* xn       = ws;              // 192*192 = 36864
    float* xt       = ws + 36864;      // 36864
    float* cosl     = ws + 73728;      // 576
    float* sum_exp  = ws + 74304;      // 192
    float* partials = ws + 74496;      // 3125*192 = 600000
    // total ~2.7 MB of ws

    k_normalize<<<M_ROWS, 64, 0, stream>>>(pred_embs, xn, xt);
    k_main<<<NBLK, 256, 0, stream>>>(weight, xt, partials);
    k_gtcos<<<BATCH * NSLOT, 64, 0, stream>>>(weight, gt_labels, xn, cosl);
    k_reduce<<<M_ROWS, 256, 0, stream>>>(partials, sum_exp);
    k_final<<<1, 64, 0, stream>>>(sum_exp, cosl, pred_ps, out);
}

// Round 3
// 136.574 us; speedup vs baseline: 1.5506x; 1.5506x over previous
//
#include <hip/hip_runtime.h>
#include <hip/hip_bf16.h>
#include <math.h>

#define N_CLASS 200000
#define DIM     192
#define BATCH   64
#define NSLOT   3
#define M_ROWS  192            // B*N
#define NBLK    3125           // 64 classes per block (2 waves x 32)

#define S_SCALE 30.0f
#define COS_M   0.9800665778412416f
#define SIN_M   0.19866933079506122f
#define TH_C    (-0.9800665778412416f)
#define MM_C    0.039733866159012245f

typedef __attribute__((ext_vector_type(8))) short bf16x8;
typedef __attribute__((ext_vector_type(4))) float f32x4;

__device__ __forceinline__ float wave_reduce_sum(float v) {
#pragma unroll
    for (int o = 32; o > 0; o >>= 1) v += __shfl_xor(v, o, 64);
    return v;
}

__device__ __forceinline__ unsigned short f2bf(float f) {
    union { __hip_bfloat16 h; unsigned short u; } v;
    v.h = __float2bfloat16(f);
    return v.u;
}

__device__ __forceinline__ bf16x8 pack8(float4 a, float4 b) {
    bf16x8 r;
    r[0] = (short)f2bf(a.x); r[1] = (short)f2bf(a.y);
    r[2] = (short)f2bf(a.z); r[3] = (short)f2bf(a.w);
    r[4] = (short)f2bf(b.x); r[5] = (short)f2bf(b.y);
    r[6] = (short)f2bf(b.z); r[7] = (short)f2bf(b.w);
    return r;
}

// ---- normalize pred_embs -> xn fp32 [row][k] and xbf bf16 [row][k] ----
__global__ void k_normalize(const float* __restrict__ pe,
                            float* __restrict__ xn, unsigned short* __restrict__ xbf) {
    int r = blockIdx.x;      // 0..191
    int l = threadIdx.x;     // 0..63
    float v0 = pe[r * DIM + l];
    float v1 = pe[r * DIM + l + 64];
    float v2 = pe[r * DIM + l + 128];
    float ss = wave_reduce_sum(v0 * v0 + v1 * v1 + v2 * v2);
    float rn = 1.0f / fmaxf(sqrtf(ss), 1e-6f);
    float a0 = v0 * rn, a1 = v1 * rn, a2 = v2 * rn;
    xn[r * DIM + l]       = a0;
    xn[r * DIM + l + 64]  = a1;
    xn[r * DIM + l + 128] = a2;
    xbf[r * DIM + l]       = f2bf(a0);
    xbf[r * DIM + l + 64]  = f2bf(a1);
    xbf[r * DIM + l + 128] = f2bf(a2);
}

// ---- gt-label cosines in exact fp32 ----
__global__ void k_gtcos(const float* __restrict__ weight, const int* __restrict__ gt,
                        const float* __restrict__ xn, float* __restrict__ cosl) {
    int i = blockIdx.x;             // b*S + s
    int b = i / NSLOT, s = i - b * NSLOT;
    int l = threadIdx.x;
    int lab = gt[b * NSLOT + s];
    const float* w = weight + (long)lab * DIM;
    float w0 = w[l], w1 = w[l + 64], w2 = w[l + 128];
    float ss = wave_reduce_sum(w0 * w0 + w1 * w1 + w2 * w2);
    float rn = 1.0f / fmaxf(sqrtf(ss), 1e-6f);
    for (int n = 0; n < NSLOT; ++n) {
        const float* x = xn + (b * NSLOT + n) * DIM;
        float d = wave_reduce_sum(w0 * x[l] + w1 * x[l + 64] + w2 * x[l + 128]);
        float c = fminf(fmaxf(d * rn, -1.0f + 1e-7f), 1.0f - 1e-7f);
        if (l == 0) cosl[(b * NSLOT + n) * NSLOT + s] = c;
    }
}

// ---- MFMA GEMM: per wave 32 classes x 192 rows, fused norm + exp-sum ----
__global__ __launch_bounds__(128) void k_main(const float* __restrict__ weight,
                                              const unsigned short* __restrict__ xbf,
                                              float* __restrict__ partials) {
    const int tid  = threadIdx.x;
    const int lane = tid & 63;
    const int wid  = tid >> 6;       // 0..1
    const int lr   = lane & 15;      // class-in-group / A-row-in-tile
    const int q    = lane >> 4;      // 0..3 -> k-quad
    const int c0w  = blockIdx.x * 64 + wid * 32;

    f32x4 acc[12][2];
#pragma unroll
    for (int t = 0; t < 12; ++t) {
        acc[t][0] = (f32x4){0.f, 0.f, 0.f, 0.f};
        acc[t][1] = (f32x4){0.f, 0.f, 0.f, 0.f};
    }
    float sq0 = 0.f, sq1 = 0.f;

    const float* wp0 = weight + (long)(c0w + lr) * DIM;
    const float* wp1 = weight + (long)(c0w + 16 + lr) * DIM;

#pragma unroll 1
    for (int s = 0; s < 6; ++s) {
        const int k0 = s * 32 + q * 8;
        float4 wa = *reinterpret_cast<const float4*>(wp0 + k0);
        float4 wb = *reinterpret_cast<const float4*>(wp0 + k0 + 4);
        float4 wc = *reinterpret_cast<const float4*>(wp1 + k0);
        float4 wd = *reinterpret_cast<const float4*>(wp1 + k0 + 4);
        sq0 += wa.x*wa.x + wa.y*wa.y + wa.z*wa.z + wa.w*wa.w
             + wb.x*wb.x + wb.y*wb.y + wb.z*wb.z + wb.w*wb.w;
        sq1 += wc.x*wc.x + wc.y*wc.y + wc.z*wc.z + wc.w*wc.w
             + wd.x*wd.x + wd.y*wd.y + wd.z*wd.z + wd.w*wd.w;
        bf16x8 b0 = pack8(wa, wb);
        bf16x8 b1 = pack8(wc, wd);
        const unsigned short* xp = xbf + lr * DIM + k0;
#pragma unroll
        for (int t = 0; t < 12; ++t) {
            bf16x8 av = *reinterpret_cast<const bf16x8*>(xp + t * 16 * DIM);
            acc[t][0] = __builtin_amdgcn_mfma_f32_16x16x32_bf16(av, b0, acc[t][0], 0, 0, 0);
            acc[t][1] = __builtin_amdgcn_mfma_f32_16x16x32_bf16(av, b1, acc[t][1], 0, 0, 0);
        }
    }

    // full class sumsq: reduce over the 4 q-groups (lanes ^16, ^32)
    sq0 += __shfl_xor(sq0, 16); sq0 += __shfl_xor(sq0, 32);
    sq1 += __shfl_xor(sq1, 16); sq1 += __shfl_xor(sq1, 32);
    float rn0 = 1.0f / fmaxf(sqrtf(sq0), 1e-6f);
    float rn1 = 1.0f / fmaxf(sqrtf(sq1), 1e-6f);

    __shared__ float red[M_ROWS * 2];

    // D layout: row = 16t + 4q + r, col(class offset) = lr  [measured m89]
#pragma unroll
    for (int t = 0; t < 12; ++t) {
#pragma unroll
        for (int r = 0; r < 4; ++r) {
            float c0v = fminf(fmaxf(acc[t][0][r] * rn0, -1.0f + 1e-7f), 1.0f - 1e-7f);
            float c1v = fminf(fmaxf(acc[t][1][r] * rn1, -1.0f + 1e-7f), 1.0f - 1e-7f);
            float e = __expf(S_SCALE * c0v - 30.0f) + __expf(S_SCALE * c1v - 30.0f);
            e += __shfl_xor(e, 1); e += __shfl_xor(e, 2);
            e += __shfl_xor(e, 4); e += __shfl_xor(e, 8);
            if (lr == 0) red[(t * 16 + q * 4 + r) * 2 + wid] = e;
        }
    }
    __syncthreads();
    // block is 128 threads but there are 192 rows: strided loop covers all
    for (int r = tid; r < M_ROWS; r += 128)
        partials[(long)blockIdx.x * M_ROWS + r] = red[r * 2] + red[r * 2 + 1];
}

// ---- deterministic reduce over 3125 block partials per row ----
__global__ void k_reduce(const float* __restrict__ partials, float* __restrict__ sum_exp) {
    int r = blockIdx.x;
    float s = 0.0f;
    for (int i = threadIdx.x; i < NBLK; i += 256)
        s += partials[(long)i * M_ROWS + r];
    s = wave_reduce_sum(s);
    __shared__ float wsm[4];
    int wid = threadIdx.x >> 6;
    if ((threadIdx.x & 63) == 0) wsm[wid] = s;
    __syncthreads();
    if (threadIdx.x == 0) sum_exp[r] = wsm[0] + wsm[1] + wsm[2] + wsm[3];
}

// ---- ce matrix, permutation argmin, final losses ----
__global__ void k_final(const float* __restrict__ sum_exp, const float* __restrict__ cosl,
                        const float* __restrict__ pred_ps, float* __restrict__ out) {
    int b = threadIdx.x;  // 0..63, one wave
    const int perms[6][3] = {{0,1,2},{0,2,1},{1,0,2},{1,2,0},{2,0,1},{2,1,0}};
    float ce[3][3];  // [n][s]
#pragma unroll
    for (int n = 0; n < 3; ++n) {
        float lse = 30.0f + logf(sum_exp[b * 3 + n]);
#pragma unroll
        for (int s = 0; s < 3; ++s) {
            float c  = cosl[(b * 3 + n) * 3 + s];
            float sl = sqrtf(fmaxf(1.0f - c * c, 1e-7f));
            float phi = c * COS_M - sl * SIN_M;
            phi = (c > TH_C) ? phi : (c - MM_C);
            float lm = lse + log1pf(expf(S_SCALE * phi - lse) - expf(S_SCALE * c - lse));
            ce[n][s] = lm - S_SCALE * phi;
        }
    }
    float best = 1e30f;
    int bp = 0;
#pragma unroll
    for (int p = 0; p < 6; ++p) {
        float cost = ce[perms[p][0]][0] + ce[perms[p][1]][1] + ce[perms[p][2]][2];
        if (cost < best) { best = cost; bp = p; }
    }
    float lspk = (ce[perms[bp][0]][0] + ce[perms[bp][1]][1] + ce[perms[bp][2]][2]) / 3.0f;

    float p0 = fminf(fmaxf(pred_ps[b * 4 + 0], 1e-6f), 1.0f - 1e-6f);
    float p1 = fminf(fmaxf(pred_ps[b * 4 + 1], 1e-6f), 1.0f - 1e-6f);
    float p2 = fminf(fmaxf(pred_ps[b * 4 + 2], 1e-6f), 1.0f - 1e-6f);
    float p3 = fminf(fmaxf(pred_ps[b * 4 + 3], 1e-6f), 1.0f - 1e-6f);
    float lcnt = -(log1pf(-p0) + log1pf(-p1) + log1pf(-p2) + logf(p3)) * 0.25f;

    float ts  = wave_reduce_sum(lspk) / 64.0f;
    float tcn = wave_reduce_sum(lcnt) / 64.0f;
    if (b == 0) {
        out[0] = ts + 0.1f * tcn;
        out[1] = ts;
        out[2] = tcn;
    }
}

extern "C" void kernel_launch(void* const* d_in, const int* in_sizes, int n_in,
                              void* d_out, int out_size, void* d_ws, size_t ws_size,
                              hipStream_t stream) {
    const float* pred_embs = (const float*)d_in[0];
    const float* pred_ps   = (const float*)d_in[1];
    const int*   gt_labels = (const int*)d_in[2];
    const float* weight    = (const float*)d_in[3];
    float* out = (float*)d_out;
    char*  ws  = (char*)d_ws;

    float*          xn       = (float*)(ws);                   // 147456 B
    unsigned short* xbf      = (unsigned short*)(ws + 147456); // 73728 B
    float*          cosl     = (float*)(ws + 221184);          // 2304 B
    float*          sum_exp  = (float*)(ws + 223488);          // 768 B
    float*          partials = (float*)(ws + 224256);          // 2.4 MB

    k_normalize<<<M_ROWS, 64, 0, stream>>>(pred_embs, xn, xbf);
    k_main<<<NBLK, 128, 0, stream>>>(weight, xbf, partials);
    k_gtcos<<<BATCH * NSLOT, 64, 0, stream>>>(weight, gt_labels, xn, cosl);
    k_reduce<<<M_ROWS, 256, 0, stream>>>(partials, sum_exp);
    k_final<<<1, 64, 0, stream>>>(sum_exp, cosl, pred_ps, out);
}

// Round 4
// 86.119 us; speedup vs baseline: 2.4590x; 1.5859x over previous
//
#include <hip/hip_runtime.h>
#include <hip/hip_bf16.h>
#include <math.h>

#define N_CLASS 200000
#define DIM     192
#define BATCH   64
#define NSLOT   3
#define M_ROWS  192            // B*N
#define BN      64             // classes per block
#define NBLK    3125           // 200000 / 64 exactly

#define S_SCALE 30.0f
#define COS_M   0.9800665778412416f
#define SIN_M   0.19866933079506122f
#define TH_C    (-0.9800665778412416f)
#define MM_C    0.039733866159012245f

typedef __attribute__((ext_vector_type(8))) short bf16x8;
typedef __attribute__((ext_vector_type(4))) float f32x4;

__device__ __forceinline__ float wave_reduce_sum(float v) {
#pragma unroll
    for (int o = 32; o > 0; o >>= 1) v += __shfl_xor(v, o, 64);
    return v;
}

__device__ __forceinline__ unsigned short f2bf(float f) {
    union { __hip_bfloat16 h; unsigned short u; } v;
    v.h = __float2bfloat16(f);
    return v.u;
}

__device__ __forceinline__ bf16x8 pack8(float4 a, float4 b) {
    bf16x8 r;
    r[0] = (short)f2bf(a.x); r[1] = (short)f2bf(a.y);
    r[2] = (short)f2bf(a.z); r[3] = (short)f2bf(a.w);
    r[4] = (short)f2bf(b.x); r[5] = (short)f2bf(b.y);
    r[6] = (short)f2bf(b.z); r[7] = (short)f2bf(b.w);
    return r;
}

__device__ __forceinline__ void gload_lds16(const void* g, void* l) {
    __builtin_amdgcn_global_load_lds(
        (const __attribute__((address_space(1))) unsigned int*)g,
        (__attribute__((address_space(3))) unsigned int*)l, 16, 0, 0);
}

// ---- normalize pred_embs -> xn fp32 [row][k] and xbf bf16 [row][k] ----
__global__ void k_normalize(const float* __restrict__ pe,
                            float* __restrict__ xn, unsigned short* __restrict__ xbf) {
    int r = blockIdx.x;      // 0..191
    int l = threadIdx.x;     // 0..63
    float v0 = pe[r * DIM + l];
    float v1 = pe[r * DIM + l + 64];
    float v2 = pe[r * DIM + l + 128];
    float ss = wave_reduce_sum(v0 * v0 + v1 * v1 + v2 * v2);
    float rn = 1.0f / fmaxf(sqrtf(ss), 1e-6f);
    float a0 = v0 * rn, a1 = v1 * rn, a2 = v2 * rn;
    xn[r * DIM + l]       = a0;
    xn[r * DIM + l + 64]  = a1;
    xn[r * DIM + l + 128] = a2;
    xbf[r * DIM + l]       = f2bf(a0);
    xbf[r * DIM + l + 64]  = f2bf(a1);
    xbf[r * DIM + l + 128] = f2bf(a2);
}

// ---- gt-label cosines in exact fp32 ----
__global__ void k_gtcos(const float* __restrict__ weight, const int* __restrict__ gt,
                        const float* __restrict__ xn, float* __restrict__ cosl) {
    int i = blockIdx.x;             // b*S + s
    int b = i / NSLOT, s = i - b * NSLOT;
    int l = threadIdx.x;
    int lab = gt[b * NSLOT + s];
    const float* w = weight + (long)lab * DIM;
    float w0 = w[l], w1 = w[l + 64], w2 = w[l + 128];
    float ss = wave_reduce_sum(w0 * w0 + w1 * w1 + w2 * w2);
    float rn = 1.0f / fmaxf(sqrtf(ss), 1e-6f);
    for (int n = 0; n < NSLOT; ++n) {
        const float* x = xn + (b * NSLOT + n) * DIM;
        float d = wave_reduce_sum(w0 * x[l] + w1 * x[l + 64] + w2 * x[l + 128]);
        float c = fminf(fmaxf(d * rn, -1.0f + 1e-7f), 1.0f - 1e-7f);
        if (l == 0) cosl[(b * NSLOT + n) * NSLOT + s] = c;
    }
}

// ---- MFMA GEMM, LDS-staged (m97 pattern), fused norm + exp-sum ----
// 512 threads = 8 waves = 4 class-groups(16) x 2 row-groups(96).
// W tile [64][32] fp32 in LDS, 16B chunks XOR-swizzled by (row&7).
// A tile [192][32] bf16 in LDS, 16B chunks XOR-swizzled by (row&3).
// Both swizzles applied on the global SOURCE address (linear LDS dest,
// required by global_load_lds) and again on the ds_read address.
__global__ __launch_bounds__(512, 4)
void k_main(const float* __restrict__ weight,
            const unsigned short* __restrict__ xbf,
            float* __restrict__ partials) {
    __shared__ __align__(16) float          Wl[2][BN * 32];      // 2 x 8 KB
    __shared__ __align__(16) unsigned short Al[2][M_ROWS * 32];  // 2 x 12 KB
    __shared__ float red[M_ROWS * 4];                            // 3 KB

    const int tid  = threadIdx.x;
    const int lane = tid & 63;
    const int wid  = tid >> 6;      // 0..7
    const int cg   = wid & 3;       // class group (16 classes)
    const int rg   = wid >> 2;      // row group  (96 rows)
    const int lr   = lane & 15;
    const int q    = lane >> 4;     // k-quad
    const int c0   = blockIdx.x * BN;

    // --- staging source offsets (pre-swizzled) ---
    // W: 512 x 16B loads/step; dst slot (row=tid>>3, chunk=tid&7)
    const int  wrow = tid >> 3, wch = tid & 7;
    const long wsrc = (long)(c0 + wrow) * DIM + ((wch ^ (wrow & 7)) << 2);
    // A: 768 x 16B loads/step; threads 0..255 do a second load
    const int arow0 = tid >> 2, ach0 = tid & 3;
    const int asrc0 = arow0 * DIM + ((ach0 ^ (arow0 & 3)) << 3);
    const int i2    = tid + 512;
    const int arow1 = i2 >> 2, ach1 = i2 & 3;
    const int asrc1 = arow1 * DIM + ((ach1 ^ (arow1 & 3)) << 3);

    // --- fragment read indices (swizzled) ---
    const int wbase = (cg * 16 + lr) * 8;                 // float4 units
    const int wc1   = (2 * q)     ^ (lr & 7);
    const int wc2   = (2 * q + 1) ^ (lr & 7);
    const int abase = (rg * 96 + lr) * 4 + (q ^ (lr & 3)); // bf16x8 units

    f32x4 acc[6];
#pragma unroll
    for (int t = 0; t < 6; ++t) acc[t] = (f32x4){0.f, 0.f, 0.f, 0.f};
    float sq = 0.f;

    // prologue: stage step 0
    gload_lds16(weight + wsrc, (char*)&Wl[0][0] + tid * 16);
    gload_lds16(xbf + asrc0, (char*)&Al[0][0] + tid * 16);
    if (tid < 256) gload_lds16(xbf + asrc1, (char*)&Al[0][0] + i2 * 16);
    __syncthreads();

#pragma unroll 1
    for (int s = 0; s < 6; ++s) {
        if (s < 5) {  // prefetch step s+1 into the buffer freed by step s-1
            int nb = (s + 1) & 1;
            gload_lds16(weight + wsrc + (s + 1) * 32, (char*)&Wl[nb][0] + tid * 16);
            gload_lds16(xbf + asrc0 + (s + 1) * 32, (char*)&Al[nb][0] + tid * 16);
            if (tid < 256)
                gload_lds16(xbf + asrc1 + (s + 1) * 32, (char*)&Al[nb][0] + i2 * 16);
        }
        const float4* W4 = (const float4*)&Wl[s & 1][0];
        const bf16x8* A8 = (const bf16x8*)&Al[s & 1][0];
        float4 wv1 = W4[wbase + wc1];   // logical k = q*8 .. q*8+3
        float4 wv2 = W4[wbase + wc2];   // logical k = q*8+4 .. q*8+7
        sq += wv1.x*wv1.x + wv1.y*wv1.y + wv1.z*wv1.z + wv1.w*wv1.w
            + wv2.x*wv2.x + wv2.y*wv2.y + wv2.z*wv2.z + wv2.w*wv2.w;
        bf16x8 b = pack8(wv1, wv2);
#pragma unroll
        for (int t = 0; t < 6; ++t) {
            bf16x8 av = A8[abase + t * 64];
            acc[t] = __builtin_amdgcn_mfma_f32_16x16x32_bf16(av, b, acc[t], 0, 0, 0);
        }
        __syncthreads();   // drains vmcnt (prefetch) + orders buffer reuse
    }

    // class norms: sum sq over the 4 q-groups (lanes ^16, ^32)
    sq += __shfl_xor(sq, 16); sq += __shfl_xor(sq, 32);
    float rn = 1.0f / fmaxf(sqrtf(sq), 1e-6f);

    // D layout: row = rg*96 + 16t + 4q + r, class col = lr  [verified R3]
#pragma unroll
    for (int t = 0; t < 6; ++t) {
#pragma unroll
        for (int r = 0; r < 4; ++r) {
            float c = fminf(fmaxf(acc[t][r] * rn, -1.0f + 1e-7f), 1.0f - 1e-7f);
            float e = __expf(S_SCALE * c - 30.0f);
            e += __shfl_xor(e, 1); e += __shfl_xor(e, 2);
            e += __shfl_xor(e, 4); e += __shfl_xor(e, 8);
            if (lr == 0) red[(rg * 96 + t * 16 + q * 4 + r) * 4 + cg] = e;
        }
    }
    __syncthreads();
    if (tid < M_ROWS)
        partials[(long)blockIdx.x * M_ROWS + tid] =
            red[tid * 4] + red[tid * 4 + 1] + red[tid * 4 + 2] + red[tid * 4 + 3];
}

// ---- deterministic reduce over 3125 block partials per row ----
__global__ void k_reduce(const float* __restrict__ partials, float* __restrict__ sum_exp) {
    int r = blockIdx.x;
    float s = 0.0f;
    for (int i = threadIdx.x; i < NBLK; i += 256)
        s += partials[(long)i * M_ROWS + r];
    s = wave_reduce_sum(s);
    __shared__ float wsm[4];
    int wid = threadIdx.x >> 6;
    if ((threadIdx.x & 63) == 0) wsm[wid] = s;
    __syncthreads();
    if (threadIdx.x == 0) sum_exp[r] = wsm[0] + wsm[1] + wsm[2] + wsm[3];
}

// ---- ce matrix, permutation argmin, final losses ----
__global__ void k_final(const float* __restrict__ sum_exp, const float* __restrict__ cosl,
                        const float* __restrict__ pred_ps, float* __restrict__ out) {
    int b = threadIdx.x;  // 0..63, one wave
    const int perms[6][3] = {{0,1,2},{0,2,1},{1,0,2},{1,2,0},{2,0,1},{2,1,0}};
    float ce[3][3];  // [n][s]
#pragma unroll
    for (int n = 0; n < 3; ++n) {
        float lse = 30.0f + logf(sum_exp[b * 3 + n]);
#pragma unroll
        for (int s = 0; s < 3; ++s) {
            float c  = cosl[(b * 3 + n) * 3 + s];
            float sl = sqrtf(fmaxf(1.0f - c * c, 1e-7f));
            float phi = c * COS_M - sl * SIN_M;
            phi = (c > TH_C) ? phi : (c - MM_C);
            float lm = lse + log1pf(expf(S_SCALE * phi - lse) - expf(S_SCALE * c - lse));
            ce[n][s] = lm - S_SCALE * phi;
        }
    }
    float best = 1e30f;
    int bp = 0;
#pragma unroll
    for (int p = 0; p < 6; ++p) {
        float cost = ce[perms[p][0]][0] + ce[perms[p][1]][1] + ce[perms[p][2]][2];
        if (cost < best) { best = cost; bp = p; }
    }
    float lspk = (ce[perms[bp][0]][0] + ce[perms[bp][1]][1] + ce[perms[bp][2]][2]) / 3.0f;

    float p0 = fminf(fmaxf(pred_ps[b * 4 + 0], 1e-6f), 1.0f - 1e-6f);
    float p1 = fminf(fmaxf(pred_ps[b * 4 + 1], 1e-6f), 1.0f - 1e-6f);
    float p2 = fminf(fmaxf(pred_ps[b * 4 + 2], 1e-6f), 1.0f - 1e-6f);
    float p3 = fminf(fmaxf(pred_ps[b * 4 + 3], 1e-6f), 1.0f - 1e-6f);
    float lcnt = -(log1pf(-p0) + log1pf(-p1) + log1pf(-p2) + logf(p3)) * 0.25f;

    float ts  = wave_reduce_sum(lspk) / 64.0f;
    float tcn = wave_reduce_sum(lcnt) / 64.0f;
    if (b == 0) {
        out[0] = ts + 0.1f * tcn;
        out[1] = ts;
        out[2] = tcn;
    }
}

extern "C" void kernel_launch(void* const* d_in, const int* in_sizes, int n_in,
                              void* d_out, int out_size, void* d_ws, size_t ws_size,
                              hipStream_t stream) {
    const float* pred_embs = (const float*)d_in[0];
    const float* pred_ps   = (const float*)d_in[1];
    const int*   gt_labels = (const int*)d_in[2];
    const float* weight    = (const float*)d_in[3];
    float* out = (float*)d_out;
    char*  ws  = (char*)d_ws;

    float*          xn       = (float*)(ws);                   // 147456 B
    unsigned short* xbf      = (unsigned short*)(ws + 147456); // 73728 B
    float*          cosl     = (float*)(ws + 221184);          // 2304 B
    float*          sum_exp  = (float*)(ws + 223488);          // 768 B
    float*          partials = (float*)(ws + 224256);          // 2.4 MB

    k_normalize<<<M_ROWS, 64, 0, stream>>>(pred_embs, xn, xbf);
    k_main<<<NBLK, 512, 0, stream>>>(weight, xbf, partials);
    k_gtcos<<<BATCH * NSLOT, 64, 0, stream>>>(weight, gt_labels, xn, cosl);
    k_reduce<<<M_ROWS, 256, 0, stream>>>(partials, sum_exp);
    k_final<<<1, 64, 0, stream>>>(sum_exp, cosl, pred_ps, out);
}